// Round 5
// baseline (629.493 us; speedup 1.0000x reference)
//
#include <hip/hip_runtime.h>

#define TSTEPS 512
#define BPG    16                 // batches per group (MFMA M)
#define NGRP   2                  // independent groups per block
#define BPB    (BPG * NGRP)       // 32 batches per block
#define ROWB   320                // bytes per A row (160 k-slots * 2B)
#define ABYTES (16 * ROWB)        // 5120 = 40*128 (swizzle-safe)

typedef short bf16x8 __attribute__((ext_vector_type(8)));
typedef float f32x4  __attribute__((ext_vector_type(4)));

__device__ __forceinline__ float fast_sigmoid(float x) {
    return __builtin_amdgcn_rcpf(1.0f + __expf(-x));
}
__device__ __forceinline__ float fast_tanh(float x) {
    return 1.0f - 2.0f * __builtin_amdgcn_rcpf(__expf(2.0f * x) + 1.0f);
}
__device__ __forceinline__ unsigned int f2bf(float f) {
    unsigned int u = __builtin_bit_cast(unsigned int, f);
    return (u + 0x7FFFu + ((u >> 16) & 1u)) >> 16;
}
__device__ __forceinline__ float bf2f(unsigned int us) {
    return __builtin_bit_cast(float, us << 16);
}
// pack (hi,lo) bf16 split of f into one dword (hi = even k-slot)
__device__ __forceinline__ unsigned int split_pack(float f) {
    unsigned int hi = f2bf(f);
    unsigned int lo = f2bf(f - bf2f(hi));
    return hi | (lo << 16);
}

// Same math as round 4 (verified): gates = [hf hi/lo (128) | x hi/lo (8) | 1 | pad] @ B
// with B rows = M = W_hr^T W_hh^T (projection composed), W_ih, bias.
// NEW: two independent 16-batch groups per block interleaved in each step
// (shared B-fragments; stalls of one chain hide under issue of the other),
// and a 3-deep static register FIFO for x (load x_{t+3} at step t).
__global__ __launch_bounds__(256, 1) void lstm_mfma2_kernel(
    const float* __restrict__ x,      // [B, T, 4]
    const float* __restrict__ W_ih,   // [256, 4]
    const float* __restrict__ W_hh,   // [256, 49]
    const float* __restrict__ b_ih,   // [256]
    const float* __restrict__ b_hh,   // [256]
    const float* __restrict__ W_hr,   // [49, 64]
    const float* __restrict__ W_out,  // [49, 49]
    const float* __restrict__ b_out,  // [49]
    float* __restrict__ out)          // [B, 49]
{
    const int tid = threadIdx.x;
    const int w   = tid >> 6;         // wave 0..3 -> hid chunk
    const int l   = tid & 63;
    const int g4  = l >> 4;
    const int ln  = l & 15;
    const int b0  = blockIdx.x * BPB;

    // A buffers: [G0cur, G0nxt, G1cur, G1nxt]
    __shared__ __align__(128) unsigned char Abuf[4 * ABYTES];
    __shared__ __align__(16)  float hf32[BPB][64];
    __shared__ float hproj[BPB][52];

    // ---------------- prologue ----------------
    for (int i = tid; i < (4 * ABYTES) / 4; i += 256)
        ((unsigned int*)Abuf)[i] = 0u;
    __syncthreads();

    // Composed recurrent matrix M[h][n] = sum_p W_hr[p][h] * W_hh[n][p]
    float Msum[4][16];
    #pragma unroll
    for (int t4 = 0; t4 < 4; ++t4)
        #pragma unroll
        for (int i = 0; i < 16; ++i) Msum[t4][i] = 0.0f;

    for (int p = 0; p < 49; ++p) {
        float wr[16];
        #pragma unroll
        for (int s = 0; s < 4; ++s)
            #pragma unroll
            for (int jp = 0; jp < 4; ++jp)
                wr[s * 4 + jp] = W_hr[p * 64 + s * 16 + g4 * 4 + jp];
        #pragma unroll
        for (int t4 = 0; t4 < 4; ++t4) {
            const float whh = W_hh[(t4 * 64 + w * 16 + ln) * 49 + p];
            #pragma unroll
            for (int i = 0; i < 16; ++i) Msum[t4][i] += whh * wr[i];
        }
    }

    bf16x8 Bf[4][5];
    union U { unsigned int d[4]; bf16x8 v; };
    #pragma unroll
    for (int t4 = 0; t4 < 4; ++t4) {
        #pragma unroll
        for (int s = 0; s < 4; ++s) {
            U u;
            #pragma unroll
            for (int jp = 0; jp < 4; ++jp) {
                const unsigned int us = f2bf(Msum[t4][s * 4 + jp]);
                u.d[jp] = us | (us << 16);
            }
            Bf[t4][s] = u.v;
        }
        U u; u.d[0] = u.d[1] = u.d[2] = u.d[3] = 0u;
        const int n = t4 * 64 + w * 16 + ln;
        if (g4 == 0) {
            #pragma unroll
            for (int c = 0; c < 4; ++c) {
                const unsigned int us = f2bf(W_ih[n * 4 + c]);
                u.d[c] = us | (us << 16);
            }
        } else if (g4 == 1) {
            u.d[0] = f2bf(b_ih[n] + b_hh[n]);
        }
        Bf[t4][4] = u.v;
    }

    // x FIFO setup (wave 0 -> G0, wave 1 -> G1)
    int xbase = 0;
    float xw = 0.f, xn = 0.f;
    if (w < 2) {
        const int batch = b0 + w * BPG + (l >> 2);
        xbase = batch * (TSTEPS * 4) + (l & 3);
        // seed x_0 into group's cur buffer
        const int row  = l >> 2;
        const int byte = (row * ROWB + 256 + 4 * (l & 3)) ^ ((row & 7) << 4);
        *(unsigned int*)(Abuf + w * 2 * ABYTES + byte) = split_pack(x[xbase]);
        xw = x[xbase + 4 * 1];        // x_1 (written during step 0)
        xn = x[xbase + 4 * 2];        // x_2
    }
    // constant-1 bias column into all four buffers
    if (tid < 64) {
        const int row = tid & 15, buf = tid >> 4;
        const int byte = (row * ROWB + 272) ^ ((row & 7) << 4);
        *(unsigned int*)(Abuf + buf * ABYTES + byte) = 0x3F80u;
    }
    __syncthreads();

    // Hoisted per-lane addresses (identical to verified round-4 layout)
    int aoff[5];
    #pragma unroll
    for (int s = 0; s < 5; ++s)
        aoff[s] = (ln * ROWB + s * 64 + g4 * 16) ^ ((ln & 7) << 4);
    int woff[4];
    #pragma unroll
    for (int r = 0; r < 4; ++r) {
        const int row = g4 * 4 + r;
        woff[r] = (row * ROWB + 4 * (w * 16 + ln)) ^ ((row & 7) << 4);
    }
    const int xwoff = ((l >> 2) * ROWB + 256 + 4 * (l & 3)) ^ (((l >> 2) & 7) << 4);

    float cst0[4] = {0.f, 0.f, 0.f, 0.f}, cst1[4] = {0.f, 0.f, 0.f, 0.f};
    float hffin0[4], hffin1[4];
    int cur = 0;

    // ---------------- recurrence ----------------
    for (int t = 0; t < TSTEPS; ++t) {
        // deep x prefetch: load x_{t+3}, consumed at step t+2 (~2.5 steps slack)
        float xn2 = 0.0f;
        if (w < 2) {
            const int tt = (t + 3 < TSTEPS) ? t + 3 : TSTEPS - 1;
            xn2 = x[xbase + 4 * tt];
        }

        const unsigned char* A0 = Abuf + cur * ABYTES;                 // G0
        const unsigned char* A1 = Abuf + 2 * ABYTES + cur * ABYTES;    // G1
        bf16x8 a0[5], a1[5];
        #pragma unroll
        for (int s = 0; s < 5; ++s) {
            a0[s] = *(const bf16x8*)(A0 + aoff[s]);
            a1[s] = *(const bf16x8*)(A1 + aoff[s]);
        }

        f32x4 aI0 = {0.f,0.f,0.f,0.f}, aF0 = aI0, aG0 = aI0, aO0 = aI0;
        f32x4 aI1 = aI0, aF1 = aI0, aG1 = aI0, aO1 = aI0;
        #pragma unroll
        for (int s = 0; s < 5; ++s) {
            aI0 = __builtin_amdgcn_mfma_f32_16x16x32_bf16(a0[s], Bf[0][s], aI0, 0, 0, 0);
            aF0 = __builtin_amdgcn_mfma_f32_16x16x32_bf16(a0[s], Bf[1][s], aF0, 0, 0, 0);
            aG0 = __builtin_amdgcn_mfma_f32_16x16x32_bf16(a0[s], Bf[2][s], aG0, 0, 0, 0);
            aO0 = __builtin_amdgcn_mfma_f32_16x16x32_bf16(a0[s], Bf[3][s], aO0, 0, 0, 0);
        }
        #pragma unroll
        for (int s = 0; s < 5; ++s) {
            aI1 = __builtin_amdgcn_mfma_f32_16x16x32_bf16(a1[s], Bf[0][s], aI1, 0, 0, 0);
            aF1 = __builtin_amdgcn_mfma_f32_16x16x32_bf16(a1[s], Bf[1][s], aF1, 0, 0, 0);
            aG1 = __builtin_amdgcn_mfma_f32_16x16x32_bf16(a1[s], Bf[2][s], aG1, 0, 0, 0);
            aO1 = __builtin_amdgcn_mfma_f32_16x16x32_bf16(a1[s], Bf[3][s], aO1, 0, 0, 0);
        }

        unsigned char* N0 = Abuf + (cur ^ 1) * ABYTES;
        unsigned char* N1 = Abuf + 2 * ABYTES + (cur ^ 1) * ABYTES;
        // group 0 nonlin first (its MFMAs finished while G1's were issuing)
        #pragma unroll
        for (int r = 0; r < 4; ++r) {
            const float gi = fast_sigmoid(aI0[r]);
            const float gf = fast_sigmoid(aF0[r]);
            const float gg = fast_tanh(aG0[r]);
            const float go = fast_sigmoid(aO0[r]);
            cst0[r] = gf * cst0[r] + gi * gg;
            const float hf = go * fast_tanh(cst0[r]);
            hffin0[r] = hf;
            *(unsigned int*)(N0 + woff[r]) = split_pack(hf);
        }
        #pragma unroll
        for (int r = 0; r < 4; ++r) {
            const float gi = fast_sigmoid(aI1[r]);
            const float gf = fast_sigmoid(aF1[r]);
            const float gg = fast_tanh(aG1[r]);
            const float go = fast_sigmoid(aO1[r]);
            cst1[r] = gf * cst1[r] + gi * gg;
            const float hf = go * fast_tanh(cst1[r]);
            hffin1[r] = hf;
            *(unsigned int*)(N1 + woff[r]) = split_pack(hf);
        }
        if (w == 0)      *(unsigned int*)(N0 + xwoff) = split_pack(xw);
        else if (w == 1) *(unsigned int*)(N1 + xwoff) = split_pack(xw);
        xw = xn; xn = xn2;

        __syncthreads();
        cur ^= 1;
    }

    // ---------------- epilogue (exact fp32 two-stage) ----------------
    #pragma unroll
    for (int r = 0; r < 4; ++r) {
        hf32[g4 * 4 + r][w * 16 + ln]       = hffin0[r];
        hf32[BPG + g4 * 4 + r][w * 16 + ln] = hffin1[r];
    }
    __syncthreads();

    for (int idx = tid; idx < BPB * 49; idx += 256) {
        const int bb = idx / 49, q = idx - bb * 49;
        float s = 0.0f;
        #pragma unroll 8
        for (int h = 0; h < 64; ++h) s += hf32[bb][h] * W_hr[q * 64 + h];
        hproj[bb][q] = s;
    }
    __syncthreads();
    for (int idx = tid; idx < BPB * 49; idx += 256) {
        const int bb = idx / 49, q2 = idx - bb * 49;
        float s = b_out[q2];
        #pragma unroll 7
        for (int p = 0; p < 49; ++p) s += hproj[bb][p] * W_out[q2 * 49 + p];
        out[(b0 + bb) * 49 + q2] = s;
    }
}

extern "C" void kernel_launch(void* const* d_in, const int* in_sizes, int n_in,
                              void* d_out, int out_size, void* d_ws, size_t ws_size,
                              hipStream_t stream) {
    (void)in_sizes; (void)n_in; (void)d_ws; (void)ws_size; (void)out_size;
    const float* x     = (const float*)d_in[0];
    const float* W_ih  = (const float*)d_in[1];
    const float* W_hh  = (const float*)d_in[2];
    const float* b_ih  = (const float*)d_in[3];
    const float* b_hh  = (const float*)d_in[4];
    const float* W_hr  = (const float*)d_in[5];
    const float* W_out = (const float*)d_in[6];
    const float* b_out = (const float*)d_in[7];
    float* outp = (float*)d_out;

    lstm_mfma2_kernel<<<dim3(2048 / BPB), dim3(256), 0, stream>>>(
        x, W_ih, W_hh, b_ih, b_hh, W_hr, W_out, b_out, outp);
}

// Round 6
// 317.654 us; speedup vs baseline: 1.9817x; 1.9817x over previous
//
#include <hip/hip_runtime.h>

#define TSTEPS 512
#define BPB    16                 // batches per block (MFMA M)
#define ROWB   256                // bytes per A row (128 k-slot capacity, 96 used)
#define ABYTES (16 * ROWB)        // 4096
#define KSTEPS 3                  // K = 96 (hf 64 | x hi/lo 8 | bias 1 | pad)

typedef short bf16x8 __attribute__((ext_vector_type(8)));
typedef float f32x4  __attribute__((ext_vector_type(4)));

__device__ __forceinline__ float fast_sigmoid(float x) {
    return __builtin_amdgcn_rcpf(1.0f + __expf(-x));
}
__device__ __forceinline__ float fast_tanh(float x) {
    return 1.0f - 2.0f * __builtin_amdgcn_rcpf(__expf(2.0f * x) + 1.0f);
}
__device__ __forceinline__ unsigned int f2bf(float f) {   // RTN-even
    unsigned int u = __builtin_bit_cast(unsigned int, f);
    return (u + 0x7FFFu + ((u >> 16) & 1u)) >> 16;
}
__device__ __forceinline__ float bf2f(unsigned int us) {
    return __builtin_bit_cast(float, us << 16);
}
__device__ __forceinline__ unsigned int split_pack(float f) {  // hi | lo<<16
    unsigned int hi = f2bf(f);
    unsigned int lo = f2bf(f - bf2f(hi));
    return hi | (lo << 16);
}

// K-slot semantics (96 slots): k<64 -> hf[k] (single bf16); 64+2c / 65+2c ->
// x_c hi/lo split; 72 -> constant 1 (bias column); 73..95 -> zero pad.
// B rows: k<64 -> M[k][n] with M = W_hr^T W_hh^T (projection composed away);
// 64+2c,65+2c -> W_ih[n][c]; 72 -> b_ih[n]+b_hh[n]; rest 0.
// Block: 4 waves, 16 batches, 128 blocks (all work on 128 CUs). Wave w owns
// gate-cols t4*64+w*16+ln for t4=0..3 (12 mfma_16x16x32_bf16 per step).
// Cell state lane-local. A double-buffered in LDS, ROWB=256 + XOR swizzle
// ((row&7)<<4) = provably conflict-free b128 reads. One barrier per step.
__global__ __launch_bounds__(256, 1) void lstm_mfma3_kernel(
    const float* __restrict__ x,      // [B, T, 4]
    const float* __restrict__ W_ih,   // [256, 4]
    const float* __restrict__ W_hh,   // [256, 49]
    const float* __restrict__ b_ih,   // [256]
    const float* __restrict__ b_hh,   // [256]
    const float* __restrict__ W_hr,   // [49, 64]
    const float* __restrict__ W_out,  // [49, 49]
    const float* __restrict__ b_out,  // [49]
    float* __restrict__ out)          // [B, 49]
{
    const int tid = threadIdx.x;
    const int w   = tid >> 6;
    const int l   = tid & 63;
    const int g4  = l >> 4;
    const int ln  = l & 15;
    const int b0  = blockIdx.x * BPB;

    __shared__ __align__(128) unsigned char Abuf[2 * ABYTES];
    __shared__ __align__(16)  float hf32[BPB][64];
    __shared__ float hproj[BPB][52];

    // ---------------- prologue ----------------
    for (int i = tid; i < (2 * ABYTES) / 4; i += 256)
        ((unsigned int*)Abuf)[i] = 0u;
    __syncthreads();

    // M[k][n] for this lane's 16 k-slots (k = s*32 + g4*8 + j, s=0,1) x 4 n-cols
    float Msum[4][16];
    #pragma unroll
    for (int t4 = 0; t4 < 4; ++t4)
        #pragma unroll
        for (int i = 0; i < 16; ++i) Msum[t4][i] = 0.0f;

    for (int p = 0; p < 49; ++p) {
        float wr[16];
        #pragma unroll
        for (int s = 0; s < 2; ++s)
            #pragma unroll
            for (int j = 0; j < 8; ++j)
                wr[s * 8 + j] = W_hr[p * 64 + s * 32 + g4 * 8 + j];
        #pragma unroll
        for (int t4 = 0; t4 < 4; ++t4) {
            const float whh = W_hh[(t4 * 64 + w * 16 + ln) * 49 + p];
            #pragma unroll
            for (int i = 0; i < 16; ++i) Msum[t4][i] += whh * wr[i];
        }
    }

    // Resident B fragments: Bf[tile][kstep]; element j = k-slot s*32+g4*8+j
    bf16x8 Bf[4][KSTEPS];
    union U { unsigned int d[4]; bf16x8 v; };
    #pragma unroll
    for (int t4 = 0; t4 < 4; ++t4) {
        #pragma unroll
        for (int s = 0; s < 2; ++s) {
            U u;
            #pragma unroll
            for (int jj = 0; jj < 4; ++jj) {
                const unsigned int e0 = f2bf(Msum[t4][s * 8 + 2 * jj]);
                const unsigned int e1 = f2bf(Msum[t4][s * 8 + 2 * jj + 1]);
                u.d[jj] = e0 | (e1 << 16);
            }
            Bf[t4][s] = u.v;
        }
        // s = 2: slots 64..95 (x hi/lo, bias, pad)
        U u; u.d[0] = u.d[1] = u.d[2] = u.d[3] = 0u;
        const int n = t4 * 64 + w * 16 + ln;
        if (g4 == 0) {                         // slots 64..71: x hi/lo pairs
            #pragma unroll
            for (int c = 0; c < 4; ++c) {
                const unsigned int us = f2bf(W_ih[n * 4 + c]);
                u.d[c] = us | (us << 16);      // hi-slot & lo-slot share W column
            }
        } else if (g4 == 1) {                  // slot 72: bias
            u.d[0] = f2bf(b_ih[n] + b_hh[n]);
        }
        Bf[t4][2] = u.v;
    }

    // x FIFO (wave 0): seed x_0, preload x_1, x_2
    int xbase = 0;
    float xw = 0.f, xn = 0.f;
    if (w == 0) {
        const int batch = b0 + (l >> 2);
        xbase = batch * (TSTEPS * 4) + (l & 3);
        const int row  = l >> 2;
        const int byte = (row * ROWB + 128 + 4 * (l & 3)) ^ ((row & 7) << 4);
        *(unsigned int*)(Abuf + byte) = split_pack(x[xbase]);
        xw = x[xbase + 4 * 1];
        xn = x[xbase + 4 * 2];
    }
    // constant-1 bias column (slot 72, byte 144) into both buffers
    if (tid < 32) {
        const int row = tid & 15, buf = tid >> 4;
        const int byte = (row * ROWB + 144) ^ ((row & 7) << 4);
        *(unsigned int*)(Abuf + buf * ABYTES + byte) = 0x3F80u;   // bf16(1.0)
    }
    __syncthreads();

    // Hoisted addresses
    int aoff[KSTEPS];
    #pragma unroll
    for (int s = 0; s < KSTEPS; ++s)
        aoff[s] = (ln * ROWB + s * 64 + g4 * 16) ^ ((ln & 7) << 4);
    int woff[4];
    #pragma unroll
    for (int r = 0; r < 4; ++r) {
        const int row = g4 * 4 + r;
        woff[r] = (row * ROWB + 2 * (w * 16 + ln)) ^ ((row & 7) << 4);
    }
    const int xwoff = ((l >> 2) * ROWB + 128 + 4 * (l & 3)) ^ (((l >> 2) & 7) << 4);

    float cst[4] = {0.f, 0.f, 0.f, 0.f};
    float hffin[4];
    int cur = 0;

    // ---------------- recurrence ----------------
    for (int t = 0; t < TSTEPS; ++t) {
        // deep x prefetch: load x_{t+3}, consumed at step t+2
        float xn2 = 0.0f;
        if (w == 0) {
            const int tt = (t + 3 < TSTEPS) ? t + 3 : TSTEPS - 1;
            xn2 = x[xbase + 4 * tt];
        }

        const unsigned char* Ab = Abuf + cur * ABYTES;
        bf16x8 af[KSTEPS];
        #pragma unroll
        for (int s = 0; s < KSTEPS; ++s)
            af[s] = *(const bf16x8*)(Ab + aoff[s]);

        f32x4 aI = {0.f, 0.f, 0.f, 0.f}, aF = aI, aG = aI, aO = aI;
        #pragma unroll
        for (int s = 0; s < KSTEPS; ++s) {
            aI = __builtin_amdgcn_mfma_f32_16x16x32_bf16(af[s], Bf[0][s], aI, 0, 0, 0);
            aF = __builtin_amdgcn_mfma_f32_16x16x32_bf16(af[s], Bf[1][s], aF, 0, 0, 0);
            aG = __builtin_amdgcn_mfma_f32_16x16x32_bf16(af[s], Bf[2][s], aG, 0, 0, 0);
            aO = __builtin_amdgcn_mfma_f32_16x16x32_bf16(af[s], Bf[3][s], aO, 0, 0, 0);
        }

        unsigned char* An = Abuf + (cur ^ 1) * ABYTES;
        #pragma unroll
        for (int r = 0; r < 4; ++r) {
            const float gi = fast_sigmoid(aI[r]);
            const float gf = fast_sigmoid(aF[r]);
            const float gg = fast_tanh(aG[r]);
            const float go = fast_sigmoid(aO[r]);
            cst[r] = gf * cst[r] + gi * gg;
            const float hf = go * fast_tanh(cst[r]);
            hffin[r] = hf;
            *(unsigned short*)(An + woff[r]) = (unsigned short)f2bf(hf);
        }
        if (w == 0)
            *(unsigned int*)(An + xwoff) = split_pack(xw);
        xw = xn; xn = xn2;

        __syncthreads();
        cur ^= 1;
    }

    // ---------------- epilogue (exact fp32 two-stage) ----------------
    #pragma unroll
    for (int r = 0; r < 4; ++r)
        hf32[g4 * 4 + r][w * 16 + ln] = hffin[r];
    __syncthreads();

    for (int idx = tid; idx < BPB * 49; idx += 256) {
        const int bb = idx / 49, q = idx - bb * 49;
        float s = 0.0f;
        #pragma unroll 8
        for (int h = 0; h < 64; ++h) s += hf32[bb][h] * W_hr[q * 64 + h];
        hproj[bb][q] = s;
    }
    __syncthreads();
    for (int idx = tid; idx < BPB * 49; idx += 256) {
        const int bb = idx / 49, q2 = idx - bb * 49;
        float s = b_out[q2];
        #pragma unroll 7
        for (int p = 0; p < 49; ++p) s += hproj[bb][p] * W_out[q2 * 49 + p];
        out[(b0 + bb) * 49 + q2] = s;
    }
}

extern "C" void kernel_launch(void* const* d_in, const int* in_sizes, int n_in,
                              void* d_out, int out_size, void* d_ws, size_t ws_size,
                              hipStream_t stream) {
    (void)in_sizes; (void)n_in; (void)d_ws; (void)ws_size; (void)out_size;
    const float* x     = (const float*)d_in[0];
    const float* W_ih  = (const float*)d_in[1];
    const float* W_hh  = (const float*)d_in[2];
    const float* b_ih  = (const float*)d_in[3];
    const float* b_hh  = (const float*)d_in[4];
    const float* W_hr  = (const float*)d_in[5];
    const float* W_out = (const float*)d_in[6];
    const float* b_out = (const float*)d_in[7];
    float* outp = (float*)d_out;

    lstm_mfma3_kernel<<<dim3(2048 / BPB), dim3(256), 0, stream>>>(
        x, W_ih, W_hh, b_ih, b_hh, W_hr, W_out, b_out, outp);
}

// Round 7
// 222.164 us; speedup vs baseline: 2.8335x; 1.4298x over previous
//
#include <hip/hip_runtime.h>

#define TSTEPS 512
#define BPB    8                  // batches per block (rows packed via perm)
#define ROWB   256                // bytes per A row (128 k-slot capacity, 96 used)
#define ABYTES (16 * ROWB)        // 4096
#define KSTEPS 3                  // K = 96 (hf 64 | x hi/lo 8 | bias 1 | pad)

typedef short bf16x8 __attribute__((ext_vector_type(8)));
typedef float f32x4  __attribute__((ext_vector_type(4)));

__device__ __forceinline__ float fast_sigmoid(float x) {
    return __builtin_amdgcn_rcpf(1.0f + __expf(-x));
}
__device__ __forceinline__ float fast_tanh(float x) {
    return 1.0f - 2.0f * __builtin_amdgcn_rcpf(__expf(2.0f * x) + 1.0f);
}
__device__ __forceinline__ unsigned int f2bf(float f) {   // RTN-even
    unsigned int u = __builtin_bit_cast(unsigned int, f);
    return (u + 0x7FFFu + ((u >> 16) & 1u)) >> 16;
}
__device__ __forceinline__ float bf2f(unsigned int us) {
    return __builtin_bit_cast(float, us << 16);
}
__device__ __forceinline__ unsigned int split_pack(float f) {  // hi | lo<<16
    unsigned int hi = f2bf(f);
    unsigned int lo = f2bf(f - bf2f(hi));
    return hi | (lo << 16);
}

// Same verified math as round 6: gates = [hf bf16 (64) | x hi/lo (8) | 1 | pad] @ B,
// B rows = M = W_hr^T W_hh^T (projection composed), W_ih, bias.
// NEW vs round 6:
//  * BPB=8, grid=256 -> ALL 256 CUs active (was 128).
//  * Batch b lives at A-row perm(b)=(b>>1)*4+(b&1) = rows {0,1,4,5,8,9,12,13}.
//    These are exactly C rows g4*4+r with r<2, so the elementwise phase runs
//    r=0..1 for every lane: per-wave transcendental ISSUE halves (trans cost
//    is per-wave-instruction; exec-masking would save nothing).
//  * x-prefetch duty spread across all 4 waves (tid%8==0) -> no wave-0 skew.
// Unused A rows stay zero (row-separable in MFMA -> harmless).
__global__ __launch_bounds__(256, 1) void lstm_mfma4_kernel(
    const float* __restrict__ x,      // [B, T, 4]
    const float* __restrict__ W_ih,   // [256, 4]
    const float* __restrict__ W_hh,   // [256, 49]
    const float* __restrict__ b_ih,   // [256]
    const float* __restrict__ b_hh,   // [256]
    const float* __restrict__ W_hr,   // [49, 64]
    const float* __restrict__ W_out,  // [49, 49]
    const float* __restrict__ b_out,  // [49]
    float* __restrict__ out)          // [B, 49]
{
    const int tid = threadIdx.x;
    const int w   = tid >> 6;
    const int l   = tid & 63;
    const int g4  = l >> 4;
    const int ln  = l & 15;
    const int b0  = blockIdx.x * BPB;

    __shared__ __align__(128) unsigned char Abuf[2 * ABYTES];
    __shared__ __align__(16)  float hf32[BPB][64];
    __shared__ float hproj[BPB][52];

    // ---------------- prologue ----------------
    for (int i = tid; i < (2 * ABYTES) / 4; i += 256)
        ((unsigned int*)Abuf)[i] = 0u;
    __syncthreads();

    // M[k][n] for this lane's 16 k-slots (k = s*32 + g4*8 + j, s=0,1) x 4 n-cols
    float Msum[4][16];
    #pragma unroll
    for (int t4 = 0; t4 < 4; ++t4)
        #pragma unroll
        for (int i = 0; i < 16; ++i) Msum[t4][i] = 0.0f;

    for (int p = 0; p < 49; ++p) {
        float wr[16];
        #pragma unroll
        for (int s = 0; s < 2; ++s)
            #pragma unroll
            for (int j = 0; j < 8; ++j)
                wr[s * 8 + j] = W_hr[p * 64 + s * 32 + g4 * 8 + j];
        #pragma unroll
        for (int t4 = 0; t4 < 4; ++t4) {
            const float whh = W_hh[(t4 * 64 + w * 16 + ln) * 49 + p];
            #pragma unroll
            for (int i = 0; i < 16; ++i) Msum[t4][i] += whh * wr[i];
        }
    }

    // Resident B fragments: Bf[tile][kstep]; element j = k-slot s*32+g4*8+j
    bf16x8 Bf[4][KSTEPS];
    union U { unsigned int d[4]; bf16x8 v; };
    #pragma unroll
    for (int t4 = 0; t4 < 4; ++t4) {
        #pragma unroll
        for (int s = 0; s < 2; ++s) {
            U u;
            #pragma unroll
            for (int jj = 0; jj < 4; ++jj) {
                const unsigned int e0 = f2bf(Msum[t4][s * 8 + 2 * jj]);
                const unsigned int e1 = f2bf(Msum[t4][s * 8 + 2 * jj + 1]);
                u.d[jj] = e0 | (e1 << 16);
            }
            Bf[t4][s] = u.v;
        }
        U u; u.d[0] = u.d[1] = u.d[2] = u.d[3] = 0u;
        const int n = t4 * 64 + w * 16 + ln;
        if (g4 == 0) {                         // slots 64..71: x hi/lo pairs
            #pragma unroll
            for (int c = 0; c < 4; ++c) {
                const unsigned int us = f2bf(W_ih[n * 4 + c]);
                u.d[c] = us | (us << 16);
            }
        } else if (g4 == 1) {                  // slot 72: bias
            u.d[0] = f2bf(b_ih[n] + b_hh[n]);
        }
        Bf[t4][2] = u.v;
    }

    // x FIFO: 32 duty lanes spread over all 4 waves (8 per wave)
    const bool xduty = ((tid & 7) == 0);
    int xbase = 0, xrowbyte = 0;
    float xw = 0.f, xn = 0.f;
    if (xduty) {
        const int v    = tid >> 3;          // 0..31
        const int bl   = v >> 2;            // local batch 0..7
        const int comp = v & 3;
        const int row  = ((bl & 6) << 1) | (bl & 1);   // perm(bl)
        xbase    = (b0 + bl) * (TSTEPS * 4) + comp;
        xrowbyte = (row * ROWB + 128 + 4 * comp) ^ ((row & 7) << 4);
        *(unsigned int*)(Abuf + xrowbyte) = split_pack(x[xbase]);   // seed x_0
        xw = x[xbase + 4 * 1];
        xn = x[xbase + 4 * 2];
    }
    // constant-1 bias column (slot 72, byte 144) into both buffers, all rows
    if (tid < 32) {
        const int row = tid & 15, buf = tid >> 4;
        const int byte = (row * ROWB + 144) ^ ((row & 7) << 4);
        *(unsigned int*)(Abuf + buf * ABYTES + byte) = 0x3F80u;   // bf16(1.0)
    }
    __syncthreads();

    // Hoisted addresses
    int aoff[KSTEPS];
    #pragma unroll
    for (int s = 0; s < KSTEPS; ++s)
        aoff[s] = (ln * ROWB + s * 64 + g4 * 16) ^ ((ln & 7) << 4);
    int woff[2];
    #pragma unroll
    for (int r = 0; r < 2; ++r) {
        const int row = g4 * 4 + r;          // in perm-set {0,1,4,5,8,9,12,13}
        woff[r] = (row * ROWB + 2 * (w * 16 + ln)) ^ ((row & 7) << 4);
    }

    float cst[2] = {0.f, 0.f};
    float hffin[2];
    int cur = 0;

    // ---------------- recurrence ----------------
    for (int t = 0; t < TSTEPS; ++t) {
        float xn2 = 0.0f;
        if (xduty) {
            const int tt = (t + 3 < TSTEPS) ? t + 3 : TSTEPS - 1;
            xn2 = x[xbase + 4 * tt];
        }

        const unsigned char* Ab = Abuf + cur * ABYTES;
        bf16x8 af[KSTEPS];
        #pragma unroll
        for (int s = 0; s < KSTEPS; ++s)
            af[s] = *(const bf16x8*)(Ab + aoff[s]);

        f32x4 aI = {0.f, 0.f, 0.f, 0.f}, aF = aI, aG = aI, aO = aI;
        #pragma unroll
        for (int s = 0; s < KSTEPS; ++s) {
            aI = __builtin_amdgcn_mfma_f32_16x16x32_bf16(af[s], Bf[0][s], aI, 0, 0, 0);
            aF = __builtin_amdgcn_mfma_f32_16x16x32_bf16(af[s], Bf[1][s], aF, 0, 0, 0);
            aG = __builtin_amdgcn_mfma_f32_16x16x32_bf16(af[s], Bf[2][s], aG, 0, 0, 0);
            aO = __builtin_amdgcn_mfma_f32_16x16x32_bf16(af[s], Bf[3][s], aO, 0, 0, 0);
        }

        unsigned char* An = Abuf + (cur ^ 1) * ABYTES;
        #pragma unroll
        for (int r = 0; r < 2; ++r) {        // only the 2 valid C rows per lane
            const float gi = fast_sigmoid(aI[r]);
            const float gf = fast_sigmoid(aF[r]);
            const float gg = fast_tanh(aG[r]);
            const float go = fast_sigmoid(aO[r]);
            cst[r] = gf * cst[r] + gi * gg;
            const float hf = go * fast_tanh(cst[r]);
            hffin[r] = hf;
            *(unsigned short*)(An + woff[r]) = (unsigned short)f2bf(hf);
        }
        if (xduty)
            *(unsigned int*)(An + xrowbyte) = split_pack(xw);
        xw = xn; xn = xn2;

        __syncthreads();
        cur ^= 1;
    }

    // ---------------- epilogue (exact fp32 two-stage) ----------------
    // C row g4*4+r -> local batch b = g4*2 + r
    #pragma unroll
    for (int r = 0; r < 2; ++r)
        hf32[g4 * 2 + r][w * 16 + ln] = hffin[r];
    __syncthreads();

    for (int idx = tid; idx < BPB * 49; idx += 256) {
        const int bb = idx / 49, q = idx - bb * 49;
        float s = 0.0f;
        #pragma unroll 8
        for (int h = 0; h < 64; ++h) s += hf32[bb][h] * W_hr[q * 64 + h];
        hproj[bb][q] = s;
    }
    __syncthreads();
    for (int idx = tid; idx < BPB * 49; idx += 256) {
        const int bb = idx / 49, q2 = idx - bb * 49;
        float s = b_out[q2];
        #pragma unroll 7
        for (int p = 0; p < 49; ++p) s += hproj[bb][p] * W_out[q2 * 49 + p];
        out[(b0 + bb) * 49 + q2] = s;
    }
}

extern "C" void kernel_launch(void* const* d_in, const int* in_sizes, int n_in,
                              void* d_out, int out_size, void* d_ws, size_t ws_size,
                              hipStream_t stream) {
    (void)in_sizes; (void)n_in; (void)d_ws; (void)ws_size; (void)out_size;
    const float* x     = (const float*)d_in[0];
    const float* W_ih  = (const float*)d_in[1];
    const float* W_hh  = (const float*)d_in[2];
    const float* b_ih  = (const float*)d_in[3];
    const float* b_hh  = (const float*)d_in[4];
    const float* W_hr  = (const float*)d_in[5];
    const float* W_out = (const float*)d_in[6];
    const float* b_out = (const float*)d_in[7];
    float* outp = (float*)d_out;

    lstm_mfma4_kernel<<<dim3(2048 / BPB), dim3(256), 0, stream>>>(
        x, W_ih, W_hh, b_ih, b_hh, W_hr, W_out, b_out, outp);
}